// Round 2
// baseline (1240.987 us; speedup 1.0000x reference)
//
#include <hip/hip_runtime.h>
#include <hip/hip_bf16.h>
#include <cstdint>

// ---------------- CSR build ----------------

__global__ void count_deg_kernel(const int* __restrict__ dst, int* __restrict__ deg, int E) {
  int i = blockIdx.x * blockDim.x + threadIdx.x;
  if (i < E) atomicAdd(&deg[dst[i]], 1);
}

// single-block exclusive scan (1024 threads, shfl-based, chunked)
__global__ void scan_kernel(const int* __restrict__ deg, int* __restrict__ ptrs, int n) {
  __shared__ int wsum[16];
  __shared__ int carry_s;
  int t = threadIdx.x;
  int lane = t & 63, wid = t >> 6;
  if (t == 0) carry_s = 0;
  __syncthreads();
  for (int base = 0; base < n; base += 1024) {
    int i = base + t;
    int v = (i < n) ? deg[i] : 0;
#pragma unroll
    for (int off = 1; off < 64; off <<= 1) {
      int u = __shfl_up(v, off, 64);
      if (lane >= off) v += u;
    }
    if (lane == 63) wsum[wid] = v;
    __syncthreads();
    int carry = carry_s;
    if (t < 16) {
      int s = wsum[t];
#pragma unroll
      for (int off = 1; off < 16; off <<= 1) {
        int u = __shfl_up(s, off, 16);
        if (t >= off) s += u;
      }
      wsum[t] = s;  // inclusive wave sums
    }
    __syncthreads();
    int woff = (wid == 0) ? 0 : wsum[wid - 1];
    if (i < n) ptrs[i + 1] = carry + woff + v;
    __syncthreads();
    if (t == 0) carry_s = carry + wsum[15];
    __syncthreads();
  }
  if (t == 0) ptrs[0] = 0;
}

__global__ void fill_csr_kernel(const int* __restrict__ src, const int* __restrict__ dst,
                                const int* __restrict__ ptrs, int* __restrict__ cnt,
                                int* __restrict__ csr_src, int* __restrict__ csr_eid, int E) {
  int i = blockIdx.x * blockDim.x + threadIdx.x;
  if (i < E) {
    int d = dst[i];
    int pos = ptrs[d] + atomicAdd(&cnt[d], 1);
    csr_src[pos] = src[i];
    csr_eid[pos] = i;
  }
}

// ---------------- Aggregation ----------------

// Layer 0: threads 0..63 sum x[src] (64 dims), threads 64..127 sum edge_attr (64 dims).
// Output aggcat[n][0:64] = sum x[src], aggcat[n][64:128] = sum edge_attr (layer-invariant).
__global__ void agg_layer0_kernel(const int* __restrict__ ptrs, const int* __restrict__ csr_src,
                                  const int* __restrict__ csr_eid,
                                  const float* __restrict__ x, const float* __restrict__ ea,
                                  float* __restrict__ aggcat, int N) {
  int n = blockIdx.x;
  int t = threadIdx.x;
  int s = ptrs[n], e = ptrs[n + 1];
  float acc = 0.f;
  if (t < 64) {
    for (int i = s; i < e; ++i) {
      int si = csr_src[i];
      acc += x[(size_t)si * 64 + t];
    }
  } else {
    int c = t - 64;
    for (int i = s; i < e; ++i) {
      int eid = csr_eid[i];
      acc += ea[(size_t)eid * 64 + c];
    }
  }
  aggcat[(size_t)n * 128 + t] = acc;
}

// Layers 1,2: sum x[src] only (128 dims)
__global__ void agg_x128_kernel(const int* __restrict__ ptrs, const int* __restrict__ csr_src,
                                const float* __restrict__ x, float* __restrict__ aggx, int N) {
  int n = blockIdx.x;
  int t = threadIdx.x;
  int s = ptrs[n], e = ptrs[n + 1];
  float acc = 0.f;
  for (int i = s; i < e; ++i) acc += x[(size_t)csr_src[i] * 128 + t];
  aggx[(size_t)n * 128 + t] = acc;
}

// ---------------- Fused node-level transform ----------------
// out[n][o] = relu( sum_p A_p[n]@W_p  + deg[n]*be[o] + br[o] ),  out width fixed 128.
// 256 threads: tile 64 nodes x 128 outs, thread micro-tile 4 nodes x 8 outs.
__global__ __launch_bounds__(256) void gemm_fused_kernel(
    const float* __restrict__ A1, int lda1, int K1, const float* __restrict__ W1,
    const float* __restrict__ A2, int lda2, int K2, const float* __restrict__ W2,
    const float* __restrict__ A3, int lda3, int K3, const float* __restrict__ W3,
    const float* __restrict__ be, const float* __restrict__ br,
    const int* __restrict__ deg, float* __restrict__ out, int N) {
  __shared__ float sA[16][65];   // +1 pad: conflict-free k-major stores
  __shared__ float sW[16][128];
  int t = threadIdx.x;
  int tx = t & 15, ty = t >> 4;
  int n0 = blockIdx.x * 64;
  float acc[4][8];
#pragma unroll
  for (int m = 0; m < 4; ++m)
#pragma unroll
    for (int j = 0; j < 8; ++j) acc[m][j] = 0.f;

  const float* As[3] = {A1, A2, A3};
  const float* Ws[3] = {W1, W2, W3};
  int ldas[3] = {lda1, lda2, lda3};
  int Ks[3] = {K1, K2, K3};

  for (int p = 0; p < 3; ++p) {
    const float* A = As[p];
    const float* W = Ws[p];
    int lda = ldas[p], K = Ks[p];
    if (K == 0) continue;
    for (int kb = 0; kb < K; kb += 16) {   // K is always a multiple of 16 (64 or 128)
#pragma unroll
      for (int r = 0; r < 4; ++r) {        // stage A chunk: 64 nodes x 16 k, transposed
        int idx = t + r * 256;
        int kk = idx & 15, nl = idx >> 4;
        int n = n0 + nl;
        sA[kk][nl] = (n < N) ? A[(size_t)n * lda + kb + kk] : 0.f;
      }
#pragma unroll
      for (int r = 0; r < 8; ++r) {        // stage W chunk: 16 k x 128 outs
        int idx = t + r * 256;
        int o = idx & 127, kk = idx >> 7;
        sW[kk][o] = W[(size_t)(kb + kk) * 128 + o];
      }
      __syncthreads();
#pragma unroll
      for (int kk = 0; kk < 16; ++kk) {
        float4 w0 = *reinterpret_cast<const float4*>(&sW[kk][tx * 8]);
        float4 w1 = *reinterpret_cast<const float4*>(&sW[kk][tx * 8 + 4]);
#pragma unroll
        for (int m = 0; m < 4; ++m) {
          float a = sA[kk][ty + 16 * m];
          acc[m][0] += a * w0.x; acc[m][1] += a * w0.y;
          acc[m][2] += a * w0.z; acc[m][3] += a * w0.w;
          acc[m][4] += a * w1.x; acc[m][5] += a * w1.y;
          acc[m][6] += a * w1.z; acc[m][7] += a * w1.w;
        }
      }
      __syncthreads();
    }
  }

  int o = tx * 8;
  float4 beA = *reinterpret_cast<const float4*>(&be[o]);
  float4 beB = *reinterpret_cast<const float4*>(&be[o + 4]);
  float4 brA = *reinterpret_cast<const float4*>(&br[o]);
  float4 brB = *reinterpret_cast<const float4*>(&br[o + 4]);
  float bev[8] = {beA.x, beA.y, beA.z, beA.w, beB.x, beB.y, beB.z, beB.w};
  float brv[8] = {brA.x, brA.y, brA.z, brA.w, brB.x, brB.y, brB.z, brB.w};
#pragma unroll
  for (int m = 0; m < 4; ++m) {
    int n = n0 + ty + 16 * m;
    if (n < N) {
      float d = (float)deg[n];
      float v[8];
#pragma unroll
      for (int j = 0; j < 8; ++j) v[j] = fmaxf(acc[m][j] + bev[j] * d + brv[j], 0.f);
      *reinterpret_cast<float4*>(&out[(size_t)n * 128 + o]) = make_float4(v[0], v[1], v[2], v[3]);
      *reinterpret_cast<float4*>(&out[(size_t)n * 128 + o + 4]) = make_float4(v[4], v[5], v[6], v[7]);
    }
  }
}

// ---------------- Graph pooling (batch is sorted) ----------------
__global__ void pool_kernel(const float* __restrict__ x, const int* __restrict__ batch,
                            float* __restrict__ out, int N) {
  int n0 = blockIdx.x * 128;
  int c = threadIdx.x;  // 128 threads, one per column
  if (n0 >= N) return;
  int end = min(n0 + 128, N);
  float acc = 0.f;
  int g = batch[n0];
  for (int n = n0; n < end; ++n) {
    int gn = batch[n];
    if (gn != g) {
      atomicAdd(&out[g * 128 + c], acc);
      acc = 0.f;
      g = gn;
    }
    acc += x[(size_t)n * 128 + c];
  }
  atomicAdd(&out[g * 128 + c], acc);
}

// ---------------- launch ----------------

extern "C" void kernel_launch(void* const* d_in, const int* in_sizes, int n_in,
                              void* d_out, int out_size, void* d_ws, size_t ws_size,
                              hipStream_t stream) {
  const float* x_in      = (const float*)d_in[0];
  const int*   edge_index = (const int*)d_in[1];
  const float* edge_attr = (const float*)d_in[2];
  const int*   batch     = (const int*)d_in[3];
  const float* We0 = (const float*)d_in[4];
  const float* be0 = (const float*)d_in[5];
  const float* Wr0 = (const float*)d_in[6];
  const float* br0 = (const float*)d_in[7];
  const float* We1 = (const float*)d_in[8];
  const float* be1 = (const float*)d_in[9];
  const float* Wr1 = (const float*)d_in[10];
  const float* br1 = (const float*)d_in[11];
  const float* We2 = (const float*)d_in[12];
  const float* be2 = (const float*)d_in[13];
  const float* Wr2 = (const float*)d_in[14];
  const float* br2 = (const float*)d_in[15];

  float* out = (float*)d_out;

  int N = in_sizes[0] / 64;   // 50000
  int E = in_sizes[1] / 2;    // 1600000
  const int* src = edge_index;
  const int* dst = edge_index + E;

  char* w = (char*)d_ws;
  size_t off = 0;
  auto alloc = [&](size_t bytes) {
    void* p = w + off;
    off += (bytes + 255) & ~(size_t)255;
    return p;
  };
  int* deg     = (int*)alloc((size_t)N * 4);
  int* cnt     = (int*)alloc((size_t)N * 4);
  size_t zero_bytes = off;  // deg + cnt must be zeroed each call
  int* ptrs    = (int*)alloc((size_t)(N + 1) * 4);
  int* csr_src = (int*)alloc((size_t)E * 4);
  int* csr_eid = (int*)alloc((size_t)E * 4);
  float* aggcat0 = (float*)alloc((size_t)N * 128 * 4);  // [aggx64 | agge64]; agge reused by layers 1,2
  float* aggx    = (float*)alloc((size_t)N * 128 * 4);
  float* xb0     = (float*)alloc((size_t)N * 128 * 4);
  float* xb1     = (float*)alloc((size_t)N * 128 * 4);

  (void)hipMemsetAsync(d_ws, 0, zero_bytes, stream);
  (void)hipMemsetAsync(d_out, 0, (size_t)out_size * sizeof(float), stream);

  int eb = (E + 255) / 256;
  count_deg_kernel<<<eb, 256, 0, stream>>>(dst, deg, E);
  scan_kernel<<<1, 1024, 0, stream>>>(deg, ptrs, N);
  fill_csr_kernel<<<eb, 256, 0, stream>>>(src, dst, ptrs, cnt, csr_src, csr_eid, E);

  int gb = (N + 63) / 64;

  // Layer 0 (in=64)
  agg_layer0_kernel<<<N, 128, 0, stream>>>(ptrs, csr_src, csr_eid, x_in, edge_attr, aggcat0, N);
  gemm_fused_kernel<<<gb, 256, 0, stream>>>(aggcat0, 128, 128, We0,
                                            x_in, 64, 64, Wr0,
                                            nullptr, 0, 0, nullptr,
                                            be0, br0, deg, xb0, N);
  // Layer 1 (in=128)
  agg_x128_kernel<<<N, 128, 0, stream>>>(ptrs, csr_src, xb0, aggx, N);
  gemm_fused_kernel<<<gb, 256, 0, stream>>>(aggx, 128, 128, We1,
                                            aggcat0 + 64, 128, 64, We1 + 128 * 128,
                                            xb0, 128, 128, Wr1,
                                            be1, br1, deg, xb1, N);
  // Layer 2 (in=128)
  agg_x128_kernel<<<N, 128, 0, stream>>>(ptrs, csr_src, xb1, aggx, N);
  gemm_fused_kernel<<<gb, 256, 0, stream>>>(aggx, 128, 128, We2,
                                            aggcat0 + 64, 128, 64, We2 + 128 * 128,
                                            xb1, 128, 128, Wr2,
                                            be2, br2, deg, xb0, N);
  // Readout
  pool_kernel<<<(N + 127) / 128, 128, 0, stream>>>(xb0, batch, out, N);
}

// Round 3
// 1006.448 us; speedup vs baseline: 1.2330x; 1.2330x over previous
//
#include <hip/hip_runtime.h>
#include <hip/hip_bf16.h>
#include <cstdint>

__device__ __forceinline__ float4 add4(float4 a, float4 b) {
  return make_float4(a.x + b.x, a.y + b.y, a.z + b.z, a.w + b.w);
}

// ---------------- CSR build ----------------

__global__ void count_deg_kernel(const int* __restrict__ dst, int* __restrict__ deg, int E) {
  int i = blockIdx.x * blockDim.x + threadIdx.x;
  if (i < E) atomicAdd(&deg[dst[i]], 1);
}

// phase 1: per-block sums of deg (512 threads/block)
__global__ void block_sum_kernel(const int* __restrict__ deg, int* __restrict__ bsum, int N) {
  int t = threadIdx.x;
  int i = blockIdx.x * 512 + t;
  int v = (i < N) ? deg[i] : 0;
#pragma unroll
  for (int off = 32; off > 0; off >>= 1) v += __shfl_down(v, off, 64);
  __shared__ int ws[8];
  int lane = t & 63, wid = t >> 6;
  if (lane == 0) ws[wid] = v;
  __syncthreads();
  if (t == 0) {
    int s = 0;
#pragma unroll
    for (int j = 0; j < 8; ++j) s += ws[j];
    bsum[blockIdx.x] = s;
  }
}

// phase 2: exclusive scan of block sums (B <= 128), one block of 128
__global__ void scan_small_kernel(const int* __restrict__ bsum, int* __restrict__ boffs, int B) {
  int t = threadIdx.x;
  int lane = t & 63, wid = t >> 6;
  int v = (t < B) ? bsum[t] : 0;
  int incl = v;
#pragma unroll
  for (int off = 1; off < 64; off <<= 1) {
    int u = __shfl_up(incl, off, 64);
    if (lane >= off) incl += u;
  }
  __shared__ int ws[2];
  if (lane == 63) ws[wid] = incl;
  __syncthreads();
  int base = (wid == 1) ? ws[0] : 0;
  if (t < B) boffs[t] = base + incl - v;  // exclusive
}

// phase 3: final ptrs (512 threads/block, same tiling as phase 1)
__global__ void ptrs_kernel(const int* __restrict__ deg, const int* __restrict__ boffs,
                            int* __restrict__ ptrs, int N) {
  int t = threadIdx.x;
  int i = blockIdx.x * 512 + t;
  int lane = t & 63, wid = t >> 6;
  int v = (i < N) ? deg[i] : 0;
  int incl = v;
#pragma unroll
  for (int off = 1; off < 64; off <<= 1) {
    int u = __shfl_up(incl, off, 64);
    if (lane >= off) incl += u;
  }
  __shared__ int ws[8];
  if (lane == 63) ws[wid] = incl;
  __syncthreads();
  if (t == 0) {
    int s = 0;
#pragma unroll
    for (int j = 0; j < 8; ++j) { int tmp = ws[j]; ws[j] = s; s += tmp; }
  }
  __syncthreads();
  if (i < N) ptrs[i + 1] = boffs[blockIdx.x] + ws[wid] + incl;  // inclusive-within + bases
  if (i == 0 && blockIdx.x == 0) ptrs[0] = 0;
}

__global__ void fill_csr_kernel(const int* __restrict__ src, const int* __restrict__ dst,
                                const int* __restrict__ ptrs, int* __restrict__ cnt,
                                int2* __restrict__ csr, int E) {
  int i = blockIdx.x * blockDim.x + threadIdx.x;
  if (i < E) {
    int d = dst[i];
    int pos = ptrs[d] + atomicAdd(&cnt[d], 1);
    csr[pos] = make_int2(src[i], i);
  }
}

// ---------------- Aggregation (float4 lanes, multi-row in flight) ----------------
// 64-float rows: 256 threads = 4 waves; 16 row-slots in flight; float4 per 16 lanes.

template <bool USE_EID>
__global__ __launch_bounds__(256) void agg64_kernel(
    const int* __restrict__ ptrs, const int2* __restrict__ csr,
    const float* __restrict__ srcdata, float* __restrict__ outagg, int N) {
  int n = blockIdx.x;
  int t = threadIdx.x;
  int lane = t & 63, w = t >> 6;
  int slot = w * 4 + (lane >> 4);
  int cg = lane & 15;
  int s = ptrs[n], e = ptrs[n + 1];
  float4 a0 = make_float4(0, 0, 0, 0), a1 = make_float4(0, 0, 0, 0);
  int i = s + slot;
  for (; i + 16 < e; i += 32) {
    int r0 = USE_EID ? csr[i].y : csr[i].x;
    int r1 = USE_EID ? csr[i + 16].y : csr[i + 16].x;
    float4 v0 = *((const float4*)(srcdata + (size_t)r0 * 64) + cg);
    float4 v1 = *((const float4*)(srcdata + (size_t)r1 * 64) + cg);
    a0 = add4(a0, v0);
    a1 = add4(a1, v1);
  }
  if (i < e) {
    int r0 = USE_EID ? csr[i].y : csr[i].x;
    a0 = add4(a0, *((const float4*)(srcdata + (size_t)r0 * 64) + cg));
  }
  a0 = add4(a0, a1);
  __shared__ float red[16][64];
  *reinterpret_cast<float4*>(&red[slot][cg * 4]) = a0;
  __syncthreads();
  if (t < 64) {
    float sum = 0.f;
#pragma unroll
    for (int r = 0; r < 16; ++r) sum += red[r][t];
    outagg[(size_t)n * 64 + t] = sum;
  }
}

// 128-float rows: 8 row-slots in flight; float4 per 32 lanes.
__global__ __launch_bounds__(256) void agg_x128_kernel(
    const int* __restrict__ ptrs, const int2* __restrict__ csr,
    const float* __restrict__ x, float* __restrict__ aggx, int N) {
  int n = blockIdx.x;
  int t = threadIdx.x;
  int lane = t & 63, w = t >> 6;
  int slot = w * 2 + (lane >> 5);
  int cg = lane & 31;
  int s = ptrs[n], e = ptrs[n + 1];
  float4 a0 = make_float4(0, 0, 0, 0), a1 = make_float4(0, 0, 0, 0);
  int i = s + slot;
  for (; i + 8 < e; i += 16) {
    int r0 = csr[i].x, r1 = csr[i + 8].x;
    float4 v0 = *((const float4*)(x + (size_t)r0 * 128) + cg);
    float4 v1 = *((const float4*)(x + (size_t)r1 * 128) + cg);
    a0 = add4(a0, v0);
    a1 = add4(a1, v1);
  }
  if (i < e) {
    int r0 = csr[i].x;
    a0 = add4(a0, *((const float4*)(x + (size_t)r0 * 128) + cg));
  }
  a0 = add4(a0, a1);
  __shared__ float red[8][128];
  *reinterpret_cast<float4*>(&red[slot][cg * 4]) = a0;
  __syncthreads();
  if (t < 128) {
    float sum = 0.f;
#pragma unroll
    for (int r = 0; r < 8; ++r) sum += red[r][t];
    aggx[(size_t)n * 128 + t] = sum;
  }
}

// ---------------- Fused node-level transform ----------------
// out[n][o] = relu( sum_p A_p[n]@W_p + deg[n]*be[o] + br[o] ), out width fixed 128.
__global__ __launch_bounds__(256) void gemm_fused_kernel(
    const float* __restrict__ A1, int lda1, int K1, const float* __restrict__ W1,
    const float* __restrict__ A2, int lda2, int K2, const float* __restrict__ W2,
    const float* __restrict__ A3, int lda3, int K3, const float* __restrict__ W3,
    const float* __restrict__ be, const float* __restrict__ br,
    const int* __restrict__ deg, float* __restrict__ out, int N) {
  __shared__ float sA[16][65];
  __shared__ float sW[16][128];
  int t = threadIdx.x;
  int tx = t & 15, ty = t >> 4;
  int n0 = blockIdx.x * 64;
  float acc[4][8];
#pragma unroll
  for (int m = 0; m < 4; ++m)
#pragma unroll
    for (int j = 0; j < 8; ++j) acc[m][j] = 0.f;

  const float* As[3] = {A1, A2, A3};
  const float* Ws[3] = {W1, W2, W3};
  int ldas[3] = {lda1, lda2, lda3};
  int Ks[3] = {K1, K2, K3};

  for (int p = 0; p < 3; ++p) {
    const float* A = As[p];
    const float* W = Ws[p];
    int lda = ldas[p], K = Ks[p];
    if (K == 0) continue;
    for (int kb = 0; kb < K; kb += 16) {
#pragma unroll
      for (int r = 0; r < 4; ++r) {
        int idx = t + r * 256;
        int kk = idx & 15, nl = idx >> 4;
        int n = n0 + nl;
        sA[kk][nl] = (n < N) ? A[(size_t)n * lda + kb + kk] : 0.f;
      }
#pragma unroll
      for (int r = 0; r < 8; ++r) {
        int idx = t + r * 256;
        int o = idx & 127, kk = idx >> 7;
        sW[kk][o] = W[(size_t)(kb + kk) * 128 + o];
      }
      __syncthreads();
#pragma unroll
      for (int kk = 0; kk < 16; ++kk) {
        float4 w0 = *reinterpret_cast<const float4*>(&sW[kk][tx * 8]);
        float4 w1 = *reinterpret_cast<const float4*>(&sW[kk][tx * 8 + 4]);
#pragma unroll
        for (int m = 0; m < 4; ++m) {
          float a = sA[kk][ty + 16 * m];
          acc[m][0] += a * w0.x; acc[m][1] += a * w0.y;
          acc[m][2] += a * w0.z; acc[m][3] += a * w0.w;
          acc[m][4] += a * w1.x; acc[m][5] += a * w1.y;
          acc[m][6] += a * w1.z; acc[m][7] += a * w1.w;
        }
      }
      __syncthreads();
    }
  }

  int o = tx * 8;
  float4 beA = *reinterpret_cast<const float4*>(&be[o]);
  float4 beB = *reinterpret_cast<const float4*>(&be[o + 4]);
  float4 brA = *reinterpret_cast<const float4*>(&br[o]);
  float4 brB = *reinterpret_cast<const float4*>(&br[o + 4]);
  float bev[8] = {beA.x, beA.y, beA.z, beA.w, beB.x, beB.y, beB.z, beB.w};
  float brv[8] = {brA.x, brA.y, brA.z, brA.w, brB.x, brB.y, brB.z, brB.w};
#pragma unroll
  for (int m = 0; m < 4; ++m) {
    int n = n0 + ty + 16 * m;
    if (n < N) {
      float d = (float)deg[n];
      float v[8];
#pragma unroll
      for (int j = 0; j < 8; ++j) v[j] = fmaxf(acc[m][j] + bev[j] * d + brv[j], 0.f);
      *reinterpret_cast<float4*>(&out[(size_t)n * 128 + o]) = make_float4(v[0], v[1], v[2], v[3]);
      *reinterpret_cast<float4*>(&out[(size_t)n * 128 + o + 4]) = make_float4(v[4], v[5], v[6], v[7]);
    }
  }
}

// ---------------- Graph pooling (batch is sorted) ----------------
__global__ void pool_kernel(const float* __restrict__ x, const int* __restrict__ batch,
                            float* __restrict__ out, int N) {
  int n0 = blockIdx.x * 128;
  int c = threadIdx.x;
  if (n0 >= N) return;
  int end = min(n0 + 128, N);
  float acc = 0.f;
  int g = batch[n0];
  for (int n = n0; n < end; ++n) {
    int gn = batch[n];
    if (gn != g) {
      atomicAdd(&out[g * 128 + c], acc);
      acc = 0.f;
      g = gn;
    }
    acc += x[(size_t)n * 128 + c];
  }
  atomicAdd(&out[g * 128 + c], acc);
}

// ---------------- launch ----------------

extern "C" void kernel_launch(void* const* d_in, const int* in_sizes, int n_in,
                              void* d_out, int out_size, void* d_ws, size_t ws_size,
                              hipStream_t stream) {
  const float* x_in       = (const float*)d_in[0];
  const int*   edge_index = (const int*)d_in[1];
  const float* edge_attr  = (const float*)d_in[2];
  const int*   batch      = (const int*)d_in[3];
  const float* We0 = (const float*)d_in[4];
  const float* be0 = (const float*)d_in[5];
  const float* Wr0 = (const float*)d_in[6];
  const float* br0 = (const float*)d_in[7];
  const float* We1 = (const float*)d_in[8];
  const float* be1 = (const float*)d_in[9];
  const float* Wr1 = (const float*)d_in[10];
  const float* br1 = (const float*)d_in[11];
  const float* We2 = (const float*)d_in[12];
  const float* be2 = (const float*)d_in[13];
  const float* Wr2 = (const float*)d_in[14];
  const float* br2 = (const float*)d_in[15];

  float* out = (float*)d_out;

  int N = in_sizes[0] / 64;   // 50000
  int E = in_sizes[1] / 2;    // 1600000
  const int* src = edge_index;
  const int* dst = edge_index + E;

  char* w = (char*)d_ws;
  size_t off = 0;
  auto alloc = [&](size_t bytes) {
    void* p = w + off;
    off += (bytes + 255) & ~(size_t)255;
    return p;
  };
  int* deg   = (int*)alloc((size_t)N * 4);
  int* cnt   = (int*)alloc((size_t)N * 4);
  size_t zero_bytes = off;  // deg + cnt zeroed each call
  int* ptrs  = (int*)alloc((size_t)(N + 1) * 4);
  int* bsum  = (int*)alloc(128 * 4);
  int* boffs = (int*)alloc(128 * 4);
  int2* csr  = (int2*)alloc((size_t)E * 8);
  float* aggx64 = (float*)alloc((size_t)N * 64 * 4);
  float* agge   = (float*)alloc((size_t)N * 64 * 4);   // layer-invariant edge aggregate
  float* aggx   = (float*)alloc((size_t)N * 128 * 4);
  float* xb0    = (float*)alloc((size_t)N * 128 * 4);
  float* xb1    = (float*)alloc((size_t)N * 128 * 4);

  (void)hipMemsetAsync(d_ws, 0, zero_bytes, stream);
  (void)hipMemsetAsync(d_out, 0, (size_t)out_size * sizeof(float), stream);

  int eb = (E + 255) / 256;
  int sb = (N + 511) / 512;  // 98 blocks (<=128 required by scan_small)
  count_deg_kernel<<<eb, 256, 0, stream>>>(dst, deg, E);
  block_sum_kernel<<<sb, 512, 0, stream>>>(deg, bsum, N);
  scan_small_kernel<<<1, 128, 0, stream>>>(bsum, boffs, sb);
  ptrs_kernel<<<sb, 512, 0, stream>>>(deg, boffs, ptrs, N);
  fill_csr_kernel<<<eb, 256, 0, stream>>>(src, dst, ptrs, cnt, csr, E);

  int gb = (N + 63) / 64;

  // Edge-attr aggregate (layer-invariant) and layer-0 x aggregate
  agg64_kernel<true><<<N, 256, 0, stream>>>(ptrs, csr, edge_attr, agge, N);
  agg64_kernel<false><<<N, 256, 0, stream>>>(ptrs, csr, x_in, aggx64, N);

  // Layer 0 (in=64): [aggx64 @ We0_top] + [agge @ We0_bot] + [x @ Wr0]
  gemm_fused_kernel<<<gb, 256, 0, stream>>>(aggx64, 64, 64, We0,
                                            agge, 64, 64, We0 + 64 * 128,
                                            x_in, 64, 64, Wr0,
                                            be0, br0, deg, xb0, N);
  // Layer 1 (in=128)
  agg_x128_kernel<<<N, 256, 0, stream>>>(ptrs, csr, xb0, aggx, N);
  gemm_fused_kernel<<<gb, 256, 0, stream>>>(aggx, 128, 128, We1,
                                            agge, 64, 64, We1 + 128 * 128,
                                            xb0, 128, 128, Wr1,
                                            be1, br1, deg, xb1, N);
  // Layer 2 (in=128)
  agg_x128_kernel<<<N, 256, 0, stream>>>(ptrs, csr, xb1, aggx, N);
  gemm_fused_kernel<<<gb, 256, 0, stream>>>(aggx, 128, 128, We2,
                                            agge, 64, 64, We2 + 128 * 128,
                                            xb1, 128, 128, Wr2,
                                            be2, br2, deg, xb0, N);
  // Readout
  pool_kernel<<<(N + 127) / 128, 128, 0, stream>>>(xb0, batch, out, N);
}

// Round 5
// 585.197 us; speedup vs baseline: 2.1206x; 1.7198x over previous
//
#include <hip/hip_runtime.h>
#include <hip/hip_bf16.h>
#include <cstdint>

typedef __attribute__((ext_vector_type(8))) short short8v;
typedef __attribute__((ext_vector_type(4))) float f32x4;

__device__ __forceinline__ float4 add4(float4 a, float4 b) {
  return make_float4(a.x + b.x, a.y + b.y, a.z + b.z, a.w + b.w);
}
__device__ __forceinline__ float bf2f(unsigned short u) {
  union { unsigned int i; float f; } v; v.i = ((unsigned int)u) << 16; return v.f;
}
__device__ __forceinline__ unsigned short f2bf(float f) {
  union { float f; unsigned int i; } v; v.f = f;
  unsigned int r = v.i + 0x7fff + ((v.i >> 16) & 1);
  return (unsigned short)(r >> 16);
}

// ---------------- CSR build ----------------

__global__ void count_deg_kernel(const int* __restrict__ dst, int* __restrict__ deg, int E) {
  int i = blockIdx.x * blockDim.x + threadIdx.x;
  if (i < E) atomicAdd(&deg[dst[i]], 1);
}

__global__ void block_sum_kernel(const int* __restrict__ deg, int* __restrict__ bsum, int N) {
  int t = threadIdx.x;
  int i = blockIdx.x * 512 + t;
  int v = (i < N) ? deg[i] : 0;
#pragma unroll
  for (int off = 32; off > 0; off >>= 1) v += __shfl_down(v, off, 64);
  __shared__ int ws[8];
  int lane = t & 63, wid = t >> 6;
  if (lane == 0) ws[wid] = v;
  __syncthreads();
  if (t == 0) {
    int s = 0;
#pragma unroll
    for (int j = 0; j < 8; ++j) s += ws[j];
    bsum[blockIdx.x] = s;
  }
}

__global__ void scan_small_kernel(const int* __restrict__ bsum, int* __restrict__ boffs, int B) {
  int t = threadIdx.x;
  int lane = t & 63, wid = t >> 6;
  int v = (t < B) ? bsum[t] : 0;
  int incl = v;
#pragma unroll
  for (int off = 1; off < 64; off <<= 1) {
    int u = __shfl_up(incl, off, 64);
    if (lane >= off) incl += u;
  }
  __shared__ int ws[2];
  if (lane == 63) ws[wid] = incl;
  __syncthreads();
  int base = (wid == 1) ? ws[0] : 0;
  if (t < B) boffs[t] = base + incl - v;
}

__global__ void ptrs_kernel(const int* __restrict__ deg, const int* __restrict__ boffs,
                            int* __restrict__ ptrs, int N) {
  int t = threadIdx.x;
  int i = blockIdx.x * 512 + t;
  int lane = t & 63, wid = t >> 6;
  int v = (i < N) ? deg[i] : 0;
  int incl = v;
#pragma unroll
  for (int off = 1; off < 64; off <<= 1) {
    int u = __shfl_up(incl, off, 64);
    if (lane >= off) incl += u;
  }
  __shared__ int ws[8];
  if (lane == 63) ws[wid] = incl;
  __syncthreads();
  if (t == 0) {
    int s = 0;
#pragma unroll
    for (int j = 0; j < 8; ++j) { int tmp = ws[j]; ws[j] = s; s += tmp; }
  }
  __syncthreads();
  if (i < N) ptrs[i + 1] = boffs[blockIdx.x] + ws[wid] + incl;
  if (i == 0 && blockIdx.x == 0) ptrs[0] = 0;
}

__global__ void fill_csr_kernel(const int* __restrict__ src, const int* __restrict__ dst,
                                const int* __restrict__ ptrs, int* __restrict__ cnt,
                                int2* __restrict__ csr, int E) {
  int i = blockIdx.x * blockDim.x + threadIdx.x;
  if (i < E) {
    int d = dst[i];
    int pos = ptrs[d] + atomicAdd(&cnt[d], 1);
    csr[pos] = make_int2(src[i], i);
  }
}

// ---------------- conversions ----------------

__global__ void f2bf_stream_kernel(const float* __restrict__ in, unsigned short* __restrict__ out, int n) {
  int i = (blockIdx.x * blockDim.x + threadIdx.x) * 8;
  if (i < n) {
    float4 v0 = *(const float4*)(in + i);
    float4 v1 = *(const float4*)(in + i + 4);
    short8v o;
    o[0] = (short)f2bf(v0.x); o[1] = (short)f2bf(v0.y);
    o[2] = (short)f2bf(v0.z); o[3] = (short)f2bf(v0.w);
    o[4] = (short)f2bf(v1.x); o[5] = (short)f2bf(v1.y);
    o[6] = (short)f2bf(v1.z); o[7] = (short)f2bf(v1.w);
    *(short8v*)(out + i) = o;
  }
}

// pack Wt[c][k] = (k<rowsE ? We[k][c] : Wr[k-rowsE][c]) as bf16, Wt is [128][Ktot]
__global__ void pack_wt_kernel(const float* __restrict__ We, int rowsE,
                               const float* __restrict__ Wr, int Ktot,
                               unsigned short* __restrict__ Wt) {
  int idx = blockIdx.x * blockDim.x + threadIdx.x;
  if (idx >= 128 * Ktot) return;
  int c = idx / Ktot, k = idx % Ktot;
  float v = (k < rowsE) ? We[(size_t)k * 128 + c] : Wr[(size_t)(k - rowsE) * 128 + c];
  Wt[idx] = f2bf(v);
}

// ---------------- Aggregation ----------------

// edge_attr aggregate: fp32 gather (rows of 64 f32 = 256B, 16 lanes), bf16 out.
__global__ __launch_bounds__(256) void agg_ea_kernel(
    const int* __restrict__ ptrs, const int2* __restrict__ csr,
    const float* __restrict__ ea, unsigned short* __restrict__ agge, int N) {
  int n = blockIdx.x;
  int t = threadIdx.x;
  int slot = t >> 4, cg = t & 15;
  int s = ptrs[n], e = ptrs[n + 1];
  float4 a0 = make_float4(0, 0, 0, 0), a1 = make_float4(0, 0, 0, 0);
  int i = s + slot;
  for (; i + 16 < e; i += 32) {
    int r0 = csr[i].y, r1 = csr[i + 16].y;
    a0 = add4(a0, *((const float4*)(ea + (size_t)r0 * 64) + cg));
    a1 = add4(a1, *((const float4*)(ea + (size_t)r1 * 64) + cg));
  }
  if (i < e) {
    int r0 = csr[i].y;
    a0 = add4(a0, *((const float4*)(ea + (size_t)r0 * 64) + cg));
  }
  a0 = add4(a0, a1);
  __shared__ float red[16][64];
  *reinterpret_cast<float4*>(&red[slot][cg * 4]) = a0;
  __syncthreads();
  if (t < 64) {
    float sum = 0.f;
#pragma unroll
    for (int r = 0; r < 16; ++r) sum += red[r][t];
    agge[(size_t)n * 64 + t] = f2bf(sum);
  }
}

// bf16 gather, rows of 64 bf16 (128B): 8 lanes/row, 32 slots.
__global__ __launch_bounds__(256) void agg_bf64_kernel(
    const int* __restrict__ ptrs, const int2* __restrict__ csr,
    const unsigned short* __restrict__ xb, unsigned short* __restrict__ outagg, int N) {
  int n = blockIdx.x;
  int t = threadIdx.x;
  int slot = t >> 3, cg = t & 7;
  int s = ptrs[n], e = ptrs[n + 1];
  float a[8];
#pragma unroll
  for (int j = 0; j < 8; ++j) a[j] = 0.f;
  for (int i = s + slot; i < e; i += 32) {
    int r = csr[i].x;
    short8v v = *(const short8v*)(xb + (size_t)r * 64 + cg * 8);
#pragma unroll
    for (int j = 0; j < 8; ++j) a[j] += bf2f((unsigned short)v[j]);
  }
  __shared__ float red[32][64];
#pragma unroll
  for (int j = 0; j < 8; ++j) red[slot][cg * 8 + j] = a[j];
  __syncthreads();
  if (t < 64) {
    float sum = 0.f;
#pragma unroll
    for (int r = 0; r < 32; ++r) sum += red[r][t];
    outagg[(size_t)n * 64 + t] = f2bf(sum);
  }
}

// bf16 gather, rows of 128 bf16 (256B): 16 lanes/row, 16 slots, unroll 2.
__global__ __launch_bounds__(256) void agg_bf128_kernel(
    const int* __restrict__ ptrs, const int2* __restrict__ csr,
    const unsigned short* __restrict__ xb, unsigned short* __restrict__ outagg, int N) {
  int n = blockIdx.x;
  int t = threadIdx.x;
  int slot = t >> 4, cg = t & 15;
  int s = ptrs[n], e = ptrs[n + 1];
  float a[8];
#pragma unroll
  for (int j = 0; j < 8; ++j) a[j] = 0.f;
  int i = s + slot;
  for (; i + 16 < e; i += 32) {
    int r0 = csr[i].x, r1 = csr[i + 16].x;
    short8v v0 = *(const short8v*)(xb + (size_t)r0 * 128 + cg * 8);
    short8v v1 = *(const short8v*)(xb + (size_t)r1 * 128 + cg * 8);
#pragma unroll
    for (int j = 0; j < 8; ++j) a[j] += bf2f((unsigned short)v0[j]) + bf2f((unsigned short)v1[j]);
  }
  if (i < e) {
    int r0 = csr[i].x;
    short8v v0 = *(const short8v*)(xb + (size_t)r0 * 128 + cg * 8);
#pragma unroll
    for (int j = 0; j < 8; ++j) a[j] += bf2f((unsigned short)v0[j]);
  }
  __shared__ float red[16][128];
#pragma unroll
  for (int j = 0; j < 8; ++j) red[slot][cg * 8 + j] = a[j];
  __syncthreads();
  if (t < 128) {
    float sum = 0.f;
#pragma unroll
    for (int r = 0; r < 16; ++r) sum += red[r][t];
    outagg[(size_t)n * 128 + t] = f2bf(sum);
  }
}

// ---------------- MFMA fused transform ----------------
// out[n][o] = relu( sum_seg A_seg[n] @ W_seg + deg[n]*be[o] + br[o] ), bf16 out [N][128].
// Wt packed [128][Ktot] bf16, K-order = (A1, A2, A3).
__global__ __launch_bounds__(256) void gemm_mfma_kernel(
    const unsigned short* __restrict__ A1, int w1, int k1,
    const unsigned short* __restrict__ A2, int w2, int k2,
    const unsigned short* __restrict__ A3, int w3, int k3,
    const unsigned short* __restrict__ Wt, int Ktot,
    const float* __restrict__ be, const float* __restrict__ br,
    const int* __restrict__ deg, unsigned short* __restrict__ out, int N) {
  int t = threadIdx.x;
  int wave = t >> 6, lane = t & 63;
  int rit = lane & 15, kgrp = lane >> 4;
  int n0 = blockIdx.x * 64;
  int arow = n0 + wave * 16 + rit;
  if (arow >= N) arow = N - 1;
  f32x4 acc[8];
#pragma unroll
  for (int c = 0; c < 8; ++c) acc[c] = (f32x4){0.f, 0.f, 0.f, 0.f};

  const unsigned short* As[3] = {A1, A2, A3};
  const int wds[3] = {w1, w2, w3};
  const int ks[3] = {k1, k2, k3};
  int kbase = 0;
  for (int s = 0; s < 3; ++s) {
    const unsigned short* Arow = As[s] + (size_t)arow * wds[s] + kgrp * 8;
    int K = ks[s];
    for (int kk = 0; kk < K; kk += 32) {
      short8v a = *(const short8v*)(Arow + kk);
      int kg = kbase + kk + kgrp * 8;
#pragma unroll
      for (int c = 0; c < 8; ++c) {
        short8v b = *(const short8v*)(Wt + (size_t)(c * 16 + rit) * Ktot + kg);
        acc[c] = __builtin_amdgcn_mfma_f32_16x16x32_bf16(a, b, acc[c], 0, 0, 0);
      }
    }
    kbase += K;
  }

  // epilogue: bias + relu -> bf16 via LDS, coalesced store
  __shared__ unsigned short st[64][136];  // 136: rows stay 16B-aligned, banks spread
  float dg[4];
#pragma unroll
  for (int r = 0; r < 4; ++r) {
    int n = n0 + wave * 16 + kgrp * 4 + r;
    dg[r] = (float)deg[n < N ? n : N - 1];
  }
#pragma unroll
  for (int c = 0; c < 8; ++c) {
    int col = c * 16 + rit;
    float bev = be[col], brv = br[col];
#pragma unroll
    for (int r = 0; r < 4; ++r) {
      float v = acc[c][r] + dg[r] * bev + brv;
      st[wave * 16 + kgrp * 4 + r][col] = f2bf(fmaxf(v, 0.f));
    }
  }
  __syncthreads();
  // 64 rows x 16 col-groups of 8 shorts = 1024 pairs -> 4 iterations of 256 threads
#pragma unroll
  for (int it = 0; it < 4; ++it) {
    int idx = t + it * 256;
    int row = idx >> 4, cg = idx & 15;
    int n = n0 + row;
    if (n < N)
      *(short8v*)(out + (size_t)n * 128 + cg * 8) = *(const short8v*)(&st[row][cg * 8]);
  }
}

// ---------------- Graph pooling (batch sorted), bf16 in, fp32 out ----------------
__global__ void pool_kernel(const unsigned short* __restrict__ x, const int* __restrict__ batch,
                            float* __restrict__ out, int N) {
  int n0 = blockIdx.x * 128;
  int c = threadIdx.x;
  if (n0 >= N) return;
  int end = min(n0 + 128, N);
  float acc = 0.f;
  int g = batch[n0];
  for (int n = n0; n < end; ++n) {
    int gn = batch[n];
    if (gn != g) {
      atomicAdd(&out[g * 128 + c], acc);
      acc = 0.f;
      g = gn;
    }
    acc += bf2f(x[(size_t)n * 128 + c]);
  }
  atomicAdd(&out[g * 128 + c], acc);
}

// ---------------- launch ----------------

extern "C" void kernel_launch(void* const* d_in, const int* in_sizes, int n_in,
                              void* d_out, int out_size, void* d_ws, size_t ws_size,
                              hipStream_t stream) {
  const float* x_in       = (const float*)d_in[0];
  const int*   edge_index = (const int*)d_in[1];
  const float* edge_attr  = (const float*)d_in[2];
  const int*   batch      = (const int*)d_in[3];
  const float* We0 = (const float*)d_in[4];
  const float* be0 = (const float*)d_in[5];
  const float* Wr0 = (const float*)d_in[6];
  const float* br0 = (const float*)d_in[7];
  const float* We1 = (const float*)d_in[8];
  const float* be1 = (const float*)d_in[9];
  const float* Wr1 = (const float*)d_in[10];
  const float* br1 = (const float*)d_in[11];
  const float* We2 = (const float*)d_in[12];
  const float* be2 = (const float*)d_in[13];
  const float* Wr2 = (const float*)d_in[14];
  const float* br2 = (const float*)d_in[15];

  float* out = (float*)d_out;

  int N = in_sizes[0] / 64;   // 50000
  int E = in_sizes[1] / 2;    // 1600000
  const int* src = edge_index;
  const int* dst = edge_index + E;

  char* w = (char*)d_ws;
  size_t off = 0;
  auto alloc = [&](size_t bytes) {
    void* p = w + off;
    off += (bytes + 255) & ~(size_t)255;
    return p;
  };
  int* deg   = (int*)alloc((size_t)N * 4);
  int* cnt   = (int*)alloc((size_t)N * 4);
  size_t zero_bytes = off;  // deg + cnt zeroed each call
  int* ptrs  = (int*)alloc((size_t)(N + 1) * 4);
  int* bsum  = (int*)alloc(128 * 4);
  int* boffs = (int*)alloc(128 * 4);
  int2* csr  = (int2*)alloc((size_t)E * 8);
  unsigned short* x_bf   = (unsigned short*)alloc((size_t)N * 64 * 2);
  unsigned short* aggx64 = (unsigned short*)alloc((size_t)N * 64 * 2);
  unsigned short* agge   = (unsigned short*)alloc((size_t)N * 64 * 2);
  unsigned short* aggx   = (unsigned short*)alloc((size_t)N * 128 * 2);
  unsigned short* xb0    = (unsigned short*)alloc((size_t)N * 128 * 2);
  unsigned short* xb1    = (unsigned short*)alloc((size_t)N * 128 * 2);
  unsigned short* Wt0    = (unsigned short*)alloc((size_t)128 * 192 * 2);
  unsigned short* Wt1    = (unsigned short*)alloc((size_t)128 * 320 * 2);
  unsigned short* Wt2    = (unsigned short*)alloc((size_t)128 * 320 * 2);

  (void)hipMemsetAsync(d_ws, 0, zero_bytes, stream);
  (void)hipMemsetAsync(d_out, 0, (size_t)out_size * sizeof(float), stream);

  int eb = (E + 255) / 256;
  int sb = (N + 511) / 512;
  count_deg_kernel<<<eb, 256, 0, stream>>>(dst, deg, E);
  block_sum_kernel<<<sb, 512, 0, stream>>>(deg, bsum, N);
  scan_small_kernel<<<1, 128, 0, stream>>>(bsum, boffs, sb);
  ptrs_kernel<<<sb, 512, 0, stream>>>(deg, boffs, ptrs, N);
  fill_csr_kernel<<<eb, 256, 0, stream>>>(src, dst, ptrs, cnt, csr, E);

  // conversions (independent of CSR)
  f2bf_stream_kernel<<<(N * 64 / 8 + 255) / 256, 256, 0, stream>>>(x_in, x_bf, N * 64);
  pack_wt_kernel<<<(128 * 192 + 255) / 256, 256, 0, stream>>>(We0, 128, Wr0, 192, Wt0);
  pack_wt_kernel<<<(128 * 320 + 255) / 256, 256, 0, stream>>>(We1, 192, Wr1, 320, Wt1);
  pack_wt_kernel<<<(128 * 320 + 255) / 256, 256, 0, stream>>>(We2, 192, Wr2, 320, Wt2);

  int gb = (N + 63) / 64;

  // layer-invariant edge aggregate + layer-0 x aggregate
  agg_ea_kernel<<<N, 256, 0, stream>>>(ptrs, csr, edge_attr, agge, N);
  agg_bf64_kernel<<<N, 256, 0, stream>>>(ptrs, csr, x_bf, aggx64, N);

  // Layer 0: K-order (aggx64:We0[0:64], agge:We0[64:128], x:Wr0)
  gemm_mfma_kernel<<<gb, 256, 0, stream>>>(aggx64, 64, 64, agge, 64, 64, x_bf, 64, 64,
                                           Wt0, 192, be0, br0, deg, xb0, N);
  // Layer 1
  agg_bf128_kernel<<<N, 256, 0, stream>>>(ptrs, csr, xb0, aggx, N);
  gemm_mfma_kernel<<<gb, 256, 0, stream>>>(aggx, 128, 128, agge, 64, 64, xb0, 128, 128,
                                           Wt1, 320, be1, br1, deg, xb1, N);
  // Layer 2
  agg_bf128_kernel<<<N, 256, 0, stream>>>(ptrs, csr, xb1, aggx, N);
  gemm_mfma_kernel<<<gb, 256, 0, stream>>>(aggx, 128, 128, agge, 64, 64, xb1, 128, 128,
                                           Wt2, 320, be2, br2, deg, xb0, N);
  // Readout
  pool_kernel<<<(N + 127) / 128, 128, 0, stream>>>(xb0, batch, out, N);
}